// Round 7
// baseline (307.722 us; speedup 1.0000x reference)
//
#include <hip/hip_runtime.h>
#include <hip/hip_bf16.h>
#include <stdint.h>

// Problem constants (fixed by the reference)
#define NS   8192
#define XD   512
#define HD   2048
#define YD   512

typedef unsigned short u16;
using bf16x8 = __attribute__((ext_vector_type(8))) short;
using u16x4  = __attribute__((ext_vector_type(4))) short;
using f32x4  = __attribute__((ext_vector_type(4))) float;

__device__ __forceinline__ float bf2f(u16 u) {
  union { uint32_t i; float f; } v; v.i = ((uint32_t)u) << 16; return v.f;
}
__device__ __forceinline__ u16 f2b(float f) {
  __hip_bfloat16 hb = __float2bfloat16(f);
  return *(const u16*)&hb;
}
// dtype-adaptive element load: f32 flag ? read float : read bf16
__device__ __forceinline__ float ld_in(const void* p, int f32, size_t i) {
  return f32 ? ((const float*)p)[i] : bf2f(((const u16*)p)[i]);
}
#define GLDS(gp, lp) __builtin_amdgcn_global_load_lds( \
    (__attribute__((address_space(1))) void*)(gp),     \
    (__attribute__((address_space(3))) void*)(lp), 16, 0, 0)

// ---------------- dtype detection (round-2/3 lesson: inputs are MIXED dtype;
// detect on-device: fp32 bits read as bf16 contain wild exponents/NaN w.h.p.)
struct Args10 { const void* p[10]; int n[10]; };

__global__ void detect_kernel(Args10 a, int* __restrict__ flags) {
  const int b = blockIdx.x;
  const u16* q = (const u16*)a.p[b];
  int m = a.n[b]; if (m > 8192) m = 8192;
  int wild = 0;
  for (int i = threadIdx.x; i < m; i += blockDim.x) {
    float v = bf2f(q[i]);
    if (!(fabsf(v) <= 1000.0f)) wild = 1;   // catches huge AND NaN
  }
  if (wild) atomicOr(&flags[b], 1);
}

// ---------------- fused prep: x->bf16 (only if f32), biases->f32, y stats ---
// biasv layout: [b1m(2048) | b1l(2048) | b2m(512) | b2l(512)]
__global__ __launch_bounds__(256) void prep_kernel(
    const void* __restrict__ x, const void* __restrict__ y,
    const void* b1m, const void* b2m, const void* b1l, const void* b2l,
    const int* __restrict__ flags,
    u16* __restrict__ xb, float* __restrict__ biasv,
    float* __restrict__ Sy, float* __restrict__ Sy2) {
  const int b = blockIdx.x;
  if (b < 2048) {                      // x conversion: only needed when f32
    if (!flags[0]) return;             // bf16 input -> GEMM1 reads x directly
    const size_t base = (size_t)b * 2048 + (size_t)threadIdx.x * 8;
    alignas(16) u16 o[8];
    const float4* s = (const float4*)((const float*)x + base);
    float4 v0 = s[0], v1 = s[1];
    o[0]=f2b(v0.x); o[1]=f2b(v0.y); o[2]=f2b(v0.z); o[3]=f2b(v0.w);
    o[4]=f2b(v1.x); o[5]=f2b(v1.y); o[6]=f2b(v1.z); o[7]=f2b(v1.w);
    *(uint4*)(xb + base) = *(const uint4*)o;
  } else if (b < 2112) {               // y column stats (64 blocks x 128 rows)
    const int f = flags[1];
    const int t = threadIdx.x;
    const int r0 = (b - 2048) * 128;
    float s0 = 0.f, s1 = 0.f, q0 = 0.f, q1 = 0.f;
    for (int r = r0; r < r0 + 128; ++r) {
      float a = ld_in(y, f, (size_t)r * YD + t);
      float c = ld_in(y, f, (size_t)r * YD + t + 256);
      s0 += a; q0 += a * a;
      s1 += c; q1 += c * c;
    }
    atomicAdd(&Sy[t], s0);        atomicAdd(&Sy2[t], q0);
    atomicAdd(&Sy[t + 256], s1);  atomicAdd(&Sy2[t + 256], q1);
  } else {                             // biases
    for (int i = threadIdx.x; i < 5120; i += 256) {
      float v;
      if (i < 2048)      v = ld_in(b1m, flags[3], i);
      else if (i < 4096) v = ld_in(b1l, flags[7], i - 2048);
      else if (i < 4608) v = ld_in(b2m, flags[5], i - 4096);
      else               v = ld_in(b2l, flags[9], i - 4608);
      biasv[i] = v;
    }
  }
}

// ---------------- all 4 weight transposes in one launch --------------------
// W1t combined: [4096, 512] = W1m^T rows 0..2047, W1l^T rows 2048..4095.
__global__ __launch_bounds__(256) void transpose_all(
    const void* w1m, const void* w2m, const void* w1l, const void* w2l,
    const int* __restrict__ flags,
    u16* W1t, u16* W2tm, u16* W2tl) {
  __shared__ u16 tile[32][33];
  const int id = blockIdx.x, which = id >> 10, t = id & 1023;
  const void* in; u16* out; int R, C, fidx;
  if (which == 0)      { in = w1m; out = W1t;                      R = XD; C = HD; fidx = 2; }
  else if (which == 1) { in = w2m; out = W2tm;                     R = HD; C = YD; fidx = 4; }
  else if (which == 2) { in = w1l; out = W1t + (size_t)HD * XD;    R = XD; C = HD; fidx = 6; }
  else                 { in = w2l; out = W2tl;                     R = HD; C = YD; fidx = 8; }
  const int f = flags[fidx];
  const int nbx = C >> 5;
  const int bx = t % nbx, by = t / nbx;
  const int c0 = bx * 32, r0 = by * 32;
  const int tx = threadIdx.x & 31, ty = threadIdx.x >> 5;
  for (int i = ty; i < 32; i += 8)
    tile[i][tx] = f2b(ld_in(in, f, (size_t)(r0 + i) * C + (c0 + tx)));
  __syncthreads();
  for (int i = ty; i < 32; i += 8)
    out[(size_t)(c0 + i) * R + (r0 + tx)] = tile[tx][i];
}

// ---------------- merged GEMM1: h_{mu,lv} = relu(x @ [W1m|W1l] + b1) --------
// Round-7: OPERAND-SWAP mfma(bfr, af) -> accT frag: lane c16 = M row,
// reg (quad*4+r) = 4 consecutive N cols -> u16x4 packed 8-B stores (16 store
// instrs/lane vs 64 scalar 2-B). Serpentine N-order keeps W1t tail in L2.
__global__ __launch_bounds__(256) void gemm1_kernel(
    const void* __restrict__ xraw, const u16* __restrict__ xb,
    const u16* __restrict__ W1t,    // [4096, 512]
    const float* __restrict__ bias, // [4096]
    const int* __restrict__ flags,
    u16* __restrict__ h_mu, u16* __restrict__ h_lv) {
  constexpr int K = XD;
  __shared__ alignas(16) u16 As[128 * 64];
  __shared__ alignas(16) u16 Bs[128 * 64];

  const u16* A = flags[0] ? xb : (const u16*)xraw;

  const int tid = threadIdx.x, wid = tid >> 6, lane = tid & 63;
  const int MT = NS / 128, NT = (2 * HD) / 128;   // 64, 32
  const int id = blockIdx.x;
  const int xcd = id & 7, slot = id >> 3;
  const int m_idx = slot / NT;
  int n_idx = slot % NT;
  if (m_idx & 1) n_idx = NT - 1 - n_idx;          // serpentine for L2 reuse
  const int bm0 = (xcd * (MT >> 3) + m_idx) * 128;
  const int bn0 = n_idx * 128;

  const int mrow = (wid >> 1) * 64, ncol = (wid & 1) * 64;
  const int quad = lane >> 4, c16 = lane & 15, cswz = c16 & 7;
  const int srow = lane >> 3, sc = lane & 7;
  const int scg  = (sc ^ srow) * 8;

  f32x4 acc[4][4] = {};   // accT: [mi][ni], c16 = m-row, reg = n-col

  for (int k0 = 0; k0 < K; k0 += 64) {
#pragma unroll
    for (int j = 0; j < 4; ++j) {
      const int grp = wid * 4 + j, row = grp * 8 + srow;
      GLDS(A   + (size_t)(bm0 + row) * K + (k0 + scg), As + grp * 512);
      GLDS(W1t + (size_t)(bn0 + row) * K + (k0 + scg), Bs + grp * 512);
    }
    __syncthreads();
#pragma unroll
    for (int h = 0; h < 2; ++h) {
      const int off = ((h * 4 + quad) ^ cswz) * 8;
      bf16x8 af[4], bfr[4];
#pragma unroll
      for (int mi = 0; mi < 4; ++mi)
        af[mi] = *(const bf16x8*)&As[(mrow + mi * 16 + c16) * 64 + off];
#pragma unroll
      for (int ni = 0; ni < 4; ++ni)
        bfr[ni] = *(const bf16x8*)&Bs[(ncol + ni * 16 + c16) * 64 + off];
#pragma unroll
      for (int mi = 0; mi < 4; ++mi)
#pragma unroll
        for (int ni = 0; ni < 4; ++ni)
          acc[mi][ni] = __builtin_amdgcn_mfma_f32_16x16x32_bf16(
              bfr[ni], af[mi], acc[mi][ni], 0, 0, 0);   // SWAPPED -> C^T frag
    }
    __syncthreads();
  }

  // Epilogue: lane holds rows c16(+mi*16), 4 consecutive cols per frag.
  const bool is_lv = bn0 >= HD;
  u16* dst = is_lv ? h_lv : h_mu;
  const int cb = bn0 - (is_lv ? HD : 0);
#pragma unroll
  for (int mi = 0; mi < 4; ++mi) {
    const int grow = bm0 + mrow + mi * 16 + c16;
#pragma unroll
    for (int ni = 0; ni < 4; ++ni) {
      const int col = ncol + ni * 16 + quad * 4;
      const f32x4 bv = *(const f32x4*)&bias[bn0 + col];
      u16x4 o;
#pragma unroll
      for (int r = 0; r < 4; ++r)
        o[r] = (short)f2b(fmaxf(acc[mi][ni][r] + bv[r], 0.f));
      *(u16x4*)&dst[(size_t)grow * HD + (cb + col)] = o;
    }
  }
}

// ---------------- dual-head GEMM2 + fused loss ------------------------------
// Round-7: one head per wave pair (waves 0-1 mu, 2-3 lv; each wave 64x64).
// ds_read per BK=32 half: 8 b128 vs round-6's 12 (1.5x less LDS pressure),
// same 16 MFMA. lv waves pass w = 0.5*exp(-tanh(lvp)) to mu waves via a
// padded LDS tile (reuses dead staging LDS after the last barrier).
__global__ __launch_bounds__(256) void gemm2_dual(
    const u16* __restrict__ hm, const u16* __restrict__ hl,
    const u16* __restrict__ W2m, const u16* __restrict__ W2l,  // [YD, HD]
    const float* __restrict__ b2m, const float* __restrict__ b2l,
    const void* __restrict__ y, const int* __restrict__ flags,
    const float* __restrict__ Sy, const float* __restrict__ Sy2,
    double* __restrict__ gacc) {
  constexpr int K = HD;
  // [Am 64x64 | Al 64x64 | Bm 128x64 | Bl 128x64] = 48 KB; w-tile (64x132 f32
  // = 33792 B) overlays from offset 0 after the final K-loop barrier.
  __shared__ alignas(16) u16 smem[25088];          // 50176 B
  u16* Am = smem;
  u16* Al = smem + 4096;
  u16* Bm = smem + 8192;
  u16* Bl = smem + 16384;
  float* wtile = (float*)smem;                     // stride 132 (bank pad)
  __shared__ double bs[4];

  const int tid = threadIdx.x, wid = tid >> 6, lane = tid & 63;
  const int MT = NS / 64, NT = YD / 128;           // 128, 4
  const int id = blockIdx.x;
  const int xcd = id & 7, slot = id >> 3;
  const int m_idx = slot / NT;
  int n_idx = slot % NT;
  if (m_idx & 1) n_idx = NT - 1 - n_idx;           // serpentine
  const int bm0 = (xcd * (MT >> 3) + m_idx) * 64;
  const int bn0 = n_idx * 128;

  const int head = wid >> 1;                       // 0 = mu, 1 = lv
  const int nbase = (wid & 1) * 64;                // cols 0-63 / 64-127
  const int quad = lane >> 4, c16 = lane & 15, cswz = c16 & 7;
  const int srow = lane >> 3, sc = lane & 7;
  const int scg  = (sc ^ srow) * 8;

  const u16* Ah = head ? Al : Am;
  const u16* Bh = head ? Bl : Bm;

  f32x4 acc[4][4] = {};   // accT: c16(+mi*16) = m-row 0..63, reg = n-col

  for (int k0 = 0; k0 < K; k0 += 64) {
#pragma unroll
    for (int j = 0; j < 2; ++j) {                  // h tiles: 64 rows each
      const int grp = wid * 2 + j, row = grp * 8 + srow;
      const size_t go = (size_t)(bm0 + row) * K + (k0 + scg);
      GLDS(hm + go, Am + grp * 512);
      GLDS(hl + go, Al + grp * 512);
    }
#pragma unroll
    for (int j = 0; j < 4; ++j) {                  // W2 tiles: 128 rows each
      const int grp = wid * 4 + j, row = grp * 8 + srow;
      const size_t go = (size_t)(bn0 + row) * K + (k0 + scg);
      GLDS(W2m + go, Bm + grp * 512);
      GLDS(W2l + go, Bl + grp * 512);
    }
    __syncthreads();
#pragma unroll
    for (int h = 0; h < 2; ++h) {
      const int off = ((h * 4 + quad) ^ cswz) * 8;
      bf16x8 af[4], bf[4];
#pragma unroll
      for (int mi = 0; mi < 4; ++mi)
        af[mi] = *(const bf16x8*)&Ah[(mi * 16 + c16) * 64 + off];
#pragma unroll
      for (int ni = 0; ni < 4; ++ni)
        bf[ni] = *(const bf16x8*)&Bh[(nbase + ni * 16 + c16) * 64 + off];
#pragma unroll
      for (int mi = 0; mi < 4; ++mi)
#pragma unroll
        for (int ni = 0; ni < 4; ++ni)
          acc[mi][ni] = __builtin_amdgcn_mfma_f32_16x16x32_bf16(
              bf[ni], af[mi], acc[mi][ni], 0, 0, 0);  // SWAPPED -> C^T frag
    }
    __syncthreads();
  }

  // ---- epilogue: lv waves hand w to mu waves through LDS ----
  if (head) {                                      // lv: w = 0.5*e^{-tanh(lvp)}
#pragma unroll
    for (int mi = 0; mi < 4; ++mi) {
      const int m_local = mi * 16 + c16;
#pragma unroll
      for (int ni = 0; ni < 4; ++ni) {
        const int colb = nbase + ni * 16 + quad * 4;
        const f32x4 bv = *(const f32x4*)&b2l[bn0 + colb];
        f32x4 wv;
#pragma unroll
        for (int r = 0; r < 4; ++r)
          wv[r] = 0.5f * expf(-tanhf(acc[mi][ni][r] + bv[r]));
        *(f32x4*)&wtile[m_local * 132 + colb] = wv;
      }
    }
  }
  __syncthreads();

  float s = 0.f;
  if (!head) {                                     // mu: loss terms
    const int yf = flags[1];
    const float invN = 1.0f / (float)NS;
#pragma unroll
    for (int mi = 0; mi < 4; ++mi) {
      const int m_local = mi * 16 + c16;
      const int grow = bm0 + m_local;
#pragma unroll
      for (int ni = 0; ni < 4; ++ni) {
        const int colb = nbase + ni * 16 + quad * 4;
        const int gcol = bn0 + colb;
        const f32x4 bv  = *(const f32x4*)&b2m[gcol];
        const f32x4 wv  = *(const f32x4*)&wtile[m_local * 132 + colb];
        const f32x4 syv = *(const f32x4*)&Sy[gcol];
        const f32x4 sy2 = *(const f32x4*)&Sy2[gcol];
        f32x4 yv;
        if (yf) {
          yv = *(const f32x4*)((const float*)y + (size_t)grow * YD + gcol);
        } else {
          u16x4 t = *(const u16x4*)((const u16*)y + (size_t)grow * YD + gcol);
#pragma unroll
          for (int r = 0; r < 4; ++r) yv[r] = bf2f((u16)t[r]);
        }
#pragma unroll
        for (int r = 0; r < 4; ++r) {
          const float m = acc[mi][ni][r] + bv[r];
          s += wv[r] * (yv[r] * yv[r] - 2.f * m * yv[r]
                        + (2.f * m * syv[r] - sy2[r]) * invN);
        }
      }
    }
  }
  for (int off = 32; off > 0; off >>= 1) s += __shfl_down(s, off);
  if (lane == 0) bs[wid] = (double)s;              // lv waves contribute 0
  __syncthreads();
  if (tid == 0) atomicAdd(gacc, bs[0] + bs[1] + bs[2] + bs[3]);
}

// Output is the reference's fp32 scalar (round-2 evidence) -> store float.
__global__ void finalize_kernel(const double* __restrict__ gacc,
                                float* __restrict__ out) {
  if (threadIdx.x == 0)
    out[0] = (float)(-gacc[0] / (double)NS);
}

// ---------------- launch ----------------
extern "C" void kernel_launch(void* const* d_in, const int* in_sizes, int n_in,
                              void* d_out, int out_size, void* d_ws, size_t ws_size,
                              hipStream_t stream) {
  char* ws = (char*)d_ws;
  double* gacc = (double*)ws;                    // [0,8)
  int*    flags = (int*)(ws + 16);               // [16,80)
  float*  Sy    = (float*)(ws + 128);            // 512 f32
  float*  Sy2   = (float*)(ws + 2176);           // 512 f32
  float*  biasv = (float*)(ws + 4224);           // 5120 f32 -> ends 24704
  u16* xb   = (u16*)(ws + 24704);                // [NS,XD] bf16, 8 MB
  u16* W1t  = xb + (size_t)NS * XD;              // [4096,512] 4 MB (both heads)
  u16* W2tm = W1t + (size_t)2 * HD * XD;         // [YD,HD] 2 MB
  u16* W2tl = W2tm + (size_t)YD * HD;            // 2 MB
  u16* h_mu = W2tl + (size_t)YD * HD;            // [NS,HD] bf16, 32 MB
  u16* h_lv = h_mu + (size_t)NS * HD;            // 32 MB  (~80 MB total)

  hipMemsetAsync(d_ws, 0, 4224, stream);         // gacc + flags + Sy + Sy2

  Args10 a;
  for (int i = 0; i < 10; ++i) { a.p[i] = d_in[i]; a.n[i] = in_sizes[i]; }
  detect_kernel<<<10, 256, 0, stream>>>(a, flags);

  prep_kernel<<<2113, 256, 0, stream>>>(d_in[0], d_in[1], d_in[3], d_in[5],
                                        d_in[7], d_in[9], flags, xb, biasv, Sy, Sy2);
  transpose_all<<<4096, 256, 0, stream>>>(d_in[2], d_in[4], d_in[6], d_in[8],
                                          flags, W1t, W2tm, W2tl);

  const float* b1  = biasv;               // [4096] = b1m|b1l
  const float* b2m = biasv + 4096, *b2l = biasv + 4608;

  gemm1_kernel<<<(NS / 128) * ((2 * HD) / 128), 256, 0, stream>>>(
      d_in[0], xb, W1t, b1, flags, h_mu, h_lv);

  gemm2_dual<<<(NS / 64) * (YD / 128), 256, 0, stream>>>(
      h_mu, h_lv, W2tm, W2tl, b2m, b2l, d_in[1], flags, Sy, Sy2, gacc);

  finalize_kernel<<<1, 64, 0, stream>>>(gacc, (float*)d_out);
}

// Round 8
// 247.958 us; speedup vs baseline: 1.2410x; 1.2410x over previous
//
#include <hip/hip_runtime.h>
#include <hip/hip_bf16.h>
#include <stdint.h>

// Problem constants (fixed by the reference)
#define NS   8192
#define XD   512
#define HD   2048
#define YD   512

typedef unsigned short u16;
using bf16x8 = __attribute__((ext_vector_type(8))) short;
using f32x4  = __attribute__((ext_vector_type(4))) float;

__device__ __forceinline__ float bf2f(u16 u) {
  union { uint32_t i; float f; } v; v.i = ((uint32_t)u) << 16; return v.f;
}
__device__ __forceinline__ u16 f2b(float f) {
  __hip_bfloat16 hb = __float2bfloat16(f);
  return *(const u16*)&hb;
}
// dtype-adaptive element load: f32 flag ? read float : read bf16
__device__ __forceinline__ float ld_in(const void* p, int f32, size_t i) {
  return f32 ? ((const float*)p)[i] : bf2f(((const u16*)p)[i]);
}
#define GLDS(gp, lp) __builtin_amdgcn_global_load_lds( \
    (__attribute__((address_space(1))) void*)(gp),     \
    (__attribute__((address_space(3))) void*)(lp), 16, 0, 0)

// ---------------- per-block dtype self-detection ----------------------------
// (round-2/3 lesson: inputs are MIXED dtype). fp32 bits read as bf16 contain
// wild exponents/NaN with p~0.46 per low-u16 -> a 256+ sample probe is
// conclusive (miss prob < 1e-30). n_u16 must be <= element count so the probe
// is in-bounds under either dtype. Block-uniform result; contains barriers.
__device__ __forceinline__ int probe_f32(const void* p, int n_u16, int* sflag) {
  if (threadIdx.x == 0) *sflag = 0;
  __syncthreads();
  const u16* q = (const u16*)p;
  int wild = 0;
  for (int i = threadIdx.x; i < n_u16; i += blockDim.x) {
    float v = bf2f(q[i]);
    if (!(fabsf(v) <= 1000.0f)) wild = 1;   // catches huge AND NaN
  }
  if (wild) *sflag = 1;
  __syncthreads();
  int r = *sflag;
  __syncthreads();                          // safe for back-to-back reuse
  return r;
}

// ---------------- fused prep: x->bf16, y stats, biases, 4 transposes --------
// grid: [0,2048) x-convert | [2048,2112) ystats | 2112 biases |
//       [2113, 2113+1024) 64x64-tile transposes (W1m, W2m, W1l, W2l)
// biasv layout: [b1m(2048) | b1l(2048) | b2m(512) | b2l(512)]
// W1t combined: [4096, 512] = W1m^T rows 0..2047, W1l^T rows 2048..4095.
__global__ __launch_bounds__(256) void prep_all(
    const void* __restrict__ x, const void* __restrict__ y,
    const void* w1m, const void* b1m, const void* w2m, const void* b2m,
    const void* w1l, const void* b1l, const void* w2l, const void* b2l,
    u16* __restrict__ xb, float* __restrict__ biasv,
    float* __restrict__ Sy, float* __restrict__ Sy2,
    u16* __restrict__ W1t, u16* __restrict__ W2tm, u16* __restrict__ W2tl) {
  __shared__ u16 tile[64 * 72];              // transpose staging (9216 B)
  __shared__ int sflag;
  const int b = blockIdx.x;
  const int tid = threadIdx.x;

  if (b < 2048) {                            // ---- x conversion (f32 only)
    if (!probe_f32(x, 1024, &sflag)) return; // bf16 -> gemm1 reads x directly
    const size_t base = (size_t)b * 2048 + (size_t)tid * 8;
    alignas(16) u16 o[8];
    const float4* s = (const float4*)((const float*)x + base);
    float4 v0 = s[0], v1 = s[1];
    o[0]=f2b(v0.x); o[1]=f2b(v0.y); o[2]=f2b(v0.z); o[3]=f2b(v0.w);
    o[4]=f2b(v1.x); o[5]=f2b(v1.y); o[6]=f2b(v1.z); o[7]=f2b(v1.w);
    *(uint4*)(xb + base) = *(const uint4*)o;
  } else if (b < 2112) {                     // ---- y column stats
    const int f = probe_f32(y, 1024, &sflag);
    const int r0 = (b - 2048) * 128;
    float s0 = 0.f, s1 = 0.f, q0 = 0.f, q1 = 0.f;
    for (int r = r0; r < r0 + 128; ++r) {
      float a = ld_in(y, f, (size_t)r * YD + tid);
      float c = ld_in(y, f, (size_t)r * YD + tid + 256);
      s0 += a; q0 += a * a;
      s1 += c; q1 += c * c;
    }
    atomicAdd(&Sy[tid], s0);        atomicAdd(&Sy2[tid], q0);
    atomicAdd(&Sy[tid + 256], s1);  atomicAdd(&Sy2[tid + 256], q1);
  } else if (b == 2112) {                    // ---- biases -> f32
    const int f3 = probe_f32(b1m, 1024, &sflag);
    const int f5 = probe_f32(b2m, 512, &sflag);
    const int f7 = probe_f32(b1l, 1024, &sflag);
    const int f9 = probe_f32(b2l, 512, &sflag);
    for (int i = tid; i < 5120; i += 256) {
      float v;
      if (i < 2048)      v = ld_in(b1m, f3, i);
      else if (i < 4096) v = ld_in(b1l, f7, i - 2048);
      else if (i < 4608) v = ld_in(b2m, f5, i - 4096);
      else               v = ld_in(b2l, f9, i - 4608);
      biasv[i] = v;
    }
  } else {                                   // ---- 64x64-tile transposes
    const int id = b - 2113, which = id >> 8, t = id & 255;
    const void* in; u16* out; int R, C;
    if (which == 0)      { in = w1m; out = W1t;                   R = XD; C = HD; }
    else if (which == 1) { in = w2m; out = W2tm;                  R = HD; C = YD; }
    else if (which == 2) { in = w1l; out = W1t + (size_t)HD * XD; R = XD; C = HD; }
    else                 { in = w2l; out = W2tl;                  R = HD; C = YD; }
    const int f = probe_f32(in, 1024, &sflag);
    const int nbx = C >> 6;
    const int c0 = (t % nbx) * 64, r0 = (t / nbx) * 64;
    const int r = tid >> 2, cc = (tid & 3) * 16;
    if (f) {
      const float4* s = (const float4*)((const float*)in + (size_t)(r0 + r) * C + c0 + cc);
#pragma unroll
      for (int k = 0; k < 4; ++k) {
        float4 v = s[k];
        tile[r * 72 + cc + k * 4 + 0] = f2b(v.x);
        tile[r * 72 + cc + k * 4 + 1] = f2b(v.y);
        tile[r * 72 + cc + k * 4 + 2] = f2b(v.z);
        tile[r * 72 + cc + k * 4 + 3] = f2b(v.w);
      }
    } else {
      const uint4* s = (const uint4*)((const u16*)in + (size_t)(r0 + r) * C + c0 + cc);
      *(uint4*)&tile[r * 72 + cc]     = s[0];
      *(uint4*)&tile[r * 72 + cc + 8] = s[1];
    }
    __syncthreads();
    const int i = tid >> 2, jc = (tid & 3) * 16;
    alignas(16) u16 o[16];
#pragma unroll
    for (int j = 0; j < 16; ++j) o[j] = tile[(jc + j) * 72 + i];
    uint4* dq = (uint4*)&out[(size_t)(c0 + i) * R + r0 + jc];
    dq[0] = ((const uint4*)o)[0];
    dq[1] = ((const uint4*)o)[1];
  }
}

// ---------------- merged GEMM1: h_{mu,lv} = relu(x @ [W1m|W1l] + b1) --------
// Round-6 proven structure: 128x128 tile, BK=64, XOR-swizzled LDS, XCD-aware
// decode (xcd owns M-slab, N fastest). bn0 >= HD writes h_lv.
__global__ __launch_bounds__(256) void gemm1_kernel(
    const void* __restrict__ xraw, const u16* __restrict__ xb,
    const u16* __restrict__ W1t,    // [4096, 512]
    const float* __restrict__ bias, // [4096]
    u16* __restrict__ h_mu, u16* __restrict__ h_lv) {
  constexpr int K = XD;
  __shared__ alignas(16) u16 As[128 * 64];
  __shared__ alignas(16) u16 Bs[128 * 64];
  __shared__ int sflag;

  const u16* A = probe_f32(xraw, 1024, &sflag) ? xb : (const u16*)xraw;

  const int tid = threadIdx.x, wid = tid >> 6, lane = tid & 63;
  const int MT = NS / 128, NT = (2 * HD) / 128;   // 64, 32
  const int id = blockIdx.x;
  const int xcd = id & 7, slot = id >> 3;
  const int bm0 = (xcd * (MT >> 3) + slot / NT) * 128;
  const int bn0 = (slot % NT) * 128;

  const int mrow = (wid >> 1) * 64, ncol = (wid & 1) * 64;
  const int quad = lane >> 4, c16 = lane & 15, cswz = c16 & 7;
  const int srow = lane >> 3, sc = lane & 7;
  const int scg  = (sc ^ srow) * 8;

  f32x4 acc[4][4] = {};

  for (int k0 = 0; k0 < K; k0 += 64) {
#pragma unroll
    for (int j = 0; j < 4; ++j) {
      const int grp = wid * 4 + j, row = grp * 8 + srow;
      GLDS(A   + (size_t)(bm0 + row) * K + (k0 + scg), As + grp * 512);
      GLDS(W1t + (size_t)(bn0 + row) * K + (k0 + scg), Bs + grp * 512);
    }
    __syncthreads();
#pragma unroll
    for (int h = 0; h < 2; ++h) {
      const int off = ((h * 4 + quad) ^ cswz) * 8;
      bf16x8 af[4], bfr[4];
#pragma unroll
      for (int mi = 0; mi < 4; ++mi)
        af[mi] = *(const bf16x8*)&As[(mrow + mi * 16 + c16) * 64 + off];
#pragma unroll
      for (int ni = 0; ni < 4; ++ni)
        bfr[ni] = *(const bf16x8*)&Bs[(ncol + ni * 16 + c16) * 64 + off];
#pragma unroll
      for (int mi = 0; mi < 4; ++mi)
#pragma unroll
        for (int ni = 0; ni < 4; ++ni)
          acc[mi][ni] = __builtin_amdgcn_mfma_f32_16x16x32_bf16(
              af[mi], bfr[ni], acc[mi][ni], 0, 0, 0);
    }
    __syncthreads();
  }

  // Epilogue (C/D layout m89: col = lane&15, row = quad*4 + reg)
  const bool is_lv = bn0 >= HD;
  u16* dst = is_lv ? h_lv : h_mu;
  const int cb = bn0 - (is_lv ? HD : 0);
#pragma unroll
  for (int ni = 0; ni < 4; ++ni) {
    const int gc = ncol + ni * 16 + c16;
    const float bv = bias[bn0 + gc];
#pragma unroll
    for (int mi = 0; mi < 4; ++mi)
#pragma unroll
      for (int r = 0; r < 4; ++r) {
        const int grow = bm0 + mrow + mi * 16 + quad * 4 + r;
        dst[(size_t)grow * HD + (cb + gc)] = f2b(fmaxf(acc[mi][ni][r] + bv, 0.f));
      }
  }
}

// ---------------- dual-head GEMM2 + fused loss + last-block finalize --------
// Round-6 proven structure: every wave computes BOTH heads on a 32x128 strip
// (dual accumulators, 32 MFMA per barrier); epilogue computes mu & lvp in
// registers -> loss directly. Last finishing block writes the output scalar
// (device-scope atomics + threadfence), eliminating the finalize kernel.
__global__ __launch_bounds__(256) void gemm2_dual(
    const u16* __restrict__ hm, const u16* __restrict__ hl,
    const u16* __restrict__ W2m, const u16* __restrict__ W2l,  // [YD, HD]
    const float* __restrict__ b2m, const float* __restrict__ b2l,
    const void* __restrict__ y,
    const float* __restrict__ Sy, const float* __restrict__ Sy2,
    double* __restrict__ gacc, unsigned* __restrict__ counter,
    float* __restrict__ out) {
  constexpr int K = HD;
  __shared__ alignas(16) u16 Am[64 * 64];    // 8 KB
  __shared__ alignas(16) u16 Al[64 * 64];    // 8 KB
  __shared__ alignas(16) u16 Bm[128 * 64];   // 16 KB
  __shared__ alignas(16) u16 Bl[128 * 64];   // 16 KB
  __shared__ double bs[4];
  __shared__ int sflag;

  const int yf = probe_f32(y, 1024, &sflag);

  const int tid = threadIdx.x, wid = tid >> 6, lane = tid & 63;
  const int MT = NS / 64, NT = YD / 128;     // 128, 4
  const int id = blockIdx.x;
  const int xcd = id & 7, slot = id >> 3;
  const int bm0 = (xcd * (MT >> 3) + slot / NT) * 64;
  const int bn0 = (slot % NT) * 128;

  const int mrow = (wid >> 1) * 32, ncol = (wid & 1) * 64;
  const int quad = lane >> 4, c16 = lane & 15, cswz = c16 & 7;
  const int srow = lane >> 3, sc = lane & 7;
  const int scg  = (sc ^ srow) * 8;

  f32x4 am[2][4] = {}, al[2][4] = {};

  for (int k0 = 0; k0 < K; k0 += 64) {
#pragma unroll
    for (int j = 0; j < 2; ++j) {            // h tiles: 64 rows
      const int grp = wid * 2 + j, row = grp * 8 + srow;
      const size_t go = (size_t)(bm0 + row) * K + (k0 + scg);
      GLDS(hm + go, Am + grp * 512);
      GLDS(hl + go, Al + grp * 512);
    }
#pragma unroll
    for (int j = 0; j < 4; ++j) {            // W2 tiles: 128 rows
      const int grp = wid * 4 + j, row = grp * 8 + srow;
      const size_t go = (size_t)(bn0 + row) * K + (k0 + scg);
      GLDS(W2m + go, Bm + grp * 512);
      GLDS(W2l + go, Bl + grp * 512);
    }
    __syncthreads();
#pragma unroll
    for (int h = 0; h < 2; ++h) {
      const int off = ((h * 4 + quad) ^ cswz) * 8;
      bf16x8 afm[2], afl[2], bfm[4], bfl[4];
#pragma unroll
      for (int mi = 0; mi < 2; ++mi) {
        const int rl = (mrow + mi * 16 + c16) * 64 + off;
        afm[mi] = *(const bf16x8*)&Am[rl];
        afl[mi] = *(const bf16x8*)&Al[rl];
      }
#pragma unroll
      for (int ni = 0; ni < 4; ++ni) {
        const int rl = (ncol + ni * 16 + c16) * 64 + off;
        bfm[ni] = *(const bf16x8*)&Bm[rl];
        bfl[ni] = *(const bf16x8*)&Bl[rl];
      }
#pragma unroll
      for (int mi = 0; mi < 2; ++mi)
#pragma unroll
        for (int ni = 0; ni < 4; ++ni) {
          am[mi][ni] = __builtin_amdgcn_mfma_f32_16x16x32_bf16(
              afm[mi], bfm[ni], am[mi][ni], 0, 0, 0);
          al[mi][ni] = __builtin_amdgcn_mfma_f32_16x16x32_bf16(
              afl[mi], bfl[ni], al[mi][ni], 0, 0, 0);
        }
    }
    __syncthreads();
  }

  // Fused loss epilogue: mu & lvp in registers.
  // term: w * [ y^2 - 2*mu*y + (2*mu*Sy_d - Sy2_d)/N ], w = 0.5*e^{-tanh(lvp)}
  const float invN = 1.0f / (float)NS;
  float s = 0.f;
#pragma unroll
  for (int ni = 0; ni < 4; ++ni) {
    const int gcol = bn0 + ncol + ni * 16 + c16;
    const float bmv = b2m[gcol], blv = b2l[gcol];
    const float syv = Sy[gcol], sy2v = Sy2[gcol];
#pragma unroll
    for (int mi = 0; mi < 2; ++mi)
#pragma unroll
      for (int r = 0; r < 4; ++r) {
        const int grow = bm0 + mrow + mi * 16 + quad * 4 + r;
        const float m   = am[mi][ni][r] + bmv;
        const float lvp = al[mi][ni][r] + blv;
        const float w   = 0.5f * expf(-tanhf(lvp));
        const float yv  = ld_in(y, yf, (size_t)grow * YD + gcol);
        s += w * (yv * yv - 2.f * m * yv + (2.f * m * syv - sy2v) * invN);
      }
  }
  for (int off = 32; off > 0; off >>= 1) s += __shfl_down(s, off);
  if (lane == 0) bs[wid] = (double)s;
  __syncthreads();
  if (tid == 0) {
    atomicAdd(gacc, bs[0] + bs[1] + bs[2] + bs[3]);
    __threadfence();
    const unsigned old = atomicAdd(counter, 1u);
    if (old == gridDim.x - 1) {              // last block -> finalize
      const double g = atomicAdd(gacc, 0.0); // coherent read of final sum
      out[0] = (float)(-g / (double)NS);     // fp32 output (round-2 evidence)
    }
  }
}

// ---------------- launch ----------------
extern "C" void kernel_launch(void* const* d_in, const int* in_sizes, int n_in,
                              void* d_out, int out_size, void* d_ws, size_t ws_size,
                              hipStream_t stream) {
  char* ws = (char*)d_ws;
  double*   gacc    = (double*)ws;               // [0,8)
  unsigned* counter = (unsigned*)(ws + 8);       // [8,12)
  float*    Sy      = (float*)(ws + 128);        // 512 f32
  float*    Sy2     = (float*)(ws + 2176);       // 512 f32
  float*    biasv   = (float*)(ws + 4224);       // 5120 f32 -> ends 24704
  u16* xb   = (u16*)(ws + 24704);                // [NS,XD] bf16, 8 MB
  u16* W1t  = xb + (size_t)NS * XD;              // [4096,512] 4 MB (both heads)
  u16* W2tm = W1t + (size_t)2 * HD * XD;         // [YD,HD] 2 MB
  u16* W2tl = W2tm + (size_t)YD * HD;            // 2 MB
  u16* h_mu = W2tl + (size_t)YD * HD;            // [NS,HD] bf16, 32 MB
  u16* h_lv = h_mu + (size_t)NS * HD;            // 32 MB  (~80 MB total)

  hipMemsetAsync(d_ws, 0, 4224, stream);         // gacc + counter + Sy + Sy2

  prep_all<<<2113 + 1024, 256, 0, stream>>>(
      d_in[0], d_in[1], d_in[2], d_in[3], d_in[4], d_in[5],
      d_in[6], d_in[7], d_in[8], d_in[9],
      xb, biasv, Sy, Sy2, W1t, W2tm, W2tl);

  const float* b1  = biasv;               // [4096] = b1m|b1l
  const float* b2m = biasv + 4096, *b2l = biasv + 4608;

  gemm1_kernel<<<(NS / 128) * ((2 * HD) / 128), 256, 0, stream>>>(
      d_in[0], xb, W1t, b1, h_mu, h_lv);

  gemm2_dual<<<(NS / 64) * (YD / 128), 256, 0, stream>>>(
      h_mu, h_lv, W2tm, W2tl, b2m, b2l, d_in[1], Sy, Sy2,
      gacc, counter, (float*)d_out);
}

// Round 9
// 230.141 us; speedup vs baseline: 1.3371x; 1.0774x over previous
//
#include <hip/hip_runtime.h>
#include <hip/hip_bf16.h>
#include <stdint.h>

// Problem constants (fixed by the reference)
#define NS   8192
#define XD   512
#define HD   2048
#define YD   512

typedef unsigned short u16;
using bf16x8 = __attribute__((ext_vector_type(8))) short;
using f32x4  = __attribute__((ext_vector_type(4))) float;

__device__ __forceinline__ float bf2f(u16 u) {
  union { uint32_t i; float f; } v; v.i = ((uint32_t)u) << 16; return v.f;
}
__device__ __forceinline__ u16 f2b(float f) {
  __hip_bfloat16 hb = __float2bfloat16(f);
  return *(const u16*)&hb;
}
// dtype-adaptive element load: f32 flag ? read float : read bf16
__device__ __forceinline__ float ld_in(const void* p, int f32, size_t i) {
  return f32 ? ((const float*)p)[i] : bf2f(((const u16*)p)[i]);
}
#define GLDS(gp, lp) __builtin_amdgcn_global_load_lds( \
    (__attribute__((address_space(1))) void*)(gp),     \
    (__attribute__((address_space(3))) void*)(lp), 16, 0, 0)

// ---------------- per-block dtype self-detection ----------------------------
// (round-2/3 lesson: inputs are MIXED dtype). fp32 bits read as bf16 contain
// wild exponents/NaN with p~0.46 per low-u16 -> a 256+ sample probe is
// conclusive (miss prob < 1e-30). n_u16 must be <= element count so the probe
// is in-bounds under either dtype. Block-uniform result; contains barriers.
__device__ __forceinline__ int probe_f32(const void* p, int n_u16, int* sflag) {
  if (threadIdx.x == 0) *sflag = 0;
  __syncthreads();
  const u16* q = (const u16*)p;
  int wild = 0;
  for (int i = threadIdx.x; i < n_u16; i += blockDim.x) {
    float v = bf2f(q[i]);
    if (!(fabsf(v) <= 1000.0f)) wild = 1;   // catches huge AND NaN
  }
  if (wild) *sflag = 1;
  __syncthreads();
  int r = *sflag;
  __syncthreads();                          // safe for back-to-back reuse
  return r;
}

// ---------------- fused prep: x->bf16, biases, 4 transposes -----------------
// grid: [0,2048) x-convert | 2048 biases | [2049, 2049+1024) transposes
// (round-9: ystats moved into gemm1's grid — its 64-block serial tail was
//  prep_all's 76 us long pole with the whole chip idle; now it overlaps MFMA)
// biasv layout: [b1m(2048) | b1l(2048) | b2m(512) | b2l(512)]
// W1t combined: [4096, 512] = W1m^T rows 0..2047, W1l^T rows 2048..4095.
__global__ __launch_bounds__(256) void prep_all(
    const void* __restrict__ x,
    const void* w1m, const void* b1m, const void* w2m, const void* b2m,
    const void* w1l, const void* b1l, const void* w2l, const void* b2l,
    u16* __restrict__ xb, float* __restrict__ biasv,
    u16* __restrict__ W1t, u16* __restrict__ W2tm, u16* __restrict__ W2tl) {
  __shared__ u16 tile[64 * 72];              // transpose staging (9216 B)
  __shared__ int sflag;
  const int b = blockIdx.x;
  const int tid = threadIdx.x;

  if (b < 2048) {                            // ---- x conversion (f32 only)
    if (!probe_f32(x, 1024, &sflag)) return; // bf16 -> gemm1 reads x directly
    const size_t base = (size_t)b * 2048 + (size_t)tid * 8;
    alignas(16) u16 o[8];
    const float4* s = (const float4*)((const float*)x + base);
    float4 v0 = s[0], v1 = s[1];
    o[0]=f2b(v0.x); o[1]=f2b(v0.y); o[2]=f2b(v0.z); o[3]=f2b(v0.w);
    o[4]=f2b(v1.x); o[5]=f2b(v1.y); o[6]=f2b(v1.z); o[7]=f2b(v1.w);
    *(uint4*)(xb + base) = *(const uint4*)o;
  } else if (b == 2048) {                    // ---- biases -> f32
    const int f3 = probe_f32(b1m, 1024, &sflag);
    const int f5 = probe_f32(b2m, 512, &sflag);
    const int f7 = probe_f32(b1l, 1024, &sflag);
    const int f9 = probe_f32(b2l, 512, &sflag);
    for (int i = tid; i < 5120; i += 256) {
      float v;
      if (i < 2048)      v = ld_in(b1m, f3, i);
      else if (i < 4096) v = ld_in(b1l, f7, i - 2048);
      else if (i < 4608) v = ld_in(b2m, f5, i - 4096);
      else               v = ld_in(b2l, f9, i - 4608);
      biasv[i] = v;
    }
  } else {                                   // ---- 64x64-tile transposes
    const int id = b - 2049, which = id >> 8, t = id & 255;
    const void* in; u16* out; int R, C;
    if (which == 0)      { in = w1m; out = W1t;                   R = XD; C = HD; }
    else if (which == 1) { in = w2m; out = W2tm;                  R = HD; C = YD; }
    else if (which == 2) { in = w1l; out = W1t + (size_t)HD * XD; R = XD; C = HD; }
    else                 { in = w2l; out = W2tl;                  R = HD; C = YD; }
    const int f = probe_f32(in, 1024, &sflag);
    const int nbx = C >> 6;
    const int c0 = (t % nbx) * 64, r0 = (t / nbx) * 64;
    const int r = tid >> 2, cc = (tid & 3) * 16;
    if (f) {
      const float4* s = (const float4*)((const float*)in + (size_t)(r0 + r) * C + c0 + cc);
#pragma unroll
      for (int k = 0; k < 4; ++k) {
        float4 v = s[k];
        tile[r * 72 + cc + k * 4 + 0] = f2b(v.x);
        tile[r * 72 + cc + k * 4 + 1] = f2b(v.y);
        tile[r * 72 + cc + k * 4 + 2] = f2b(v.z);
        tile[r * 72 + cc + k * 4 + 3] = f2b(v.w);
      }
    } else {
      const uint4* s = (const uint4*)((const u16*)in + (size_t)(r0 + r) * C + c0 + cc);
      *(uint4*)&tile[r * 72 + cc]     = s[0];
      *(uint4*)&tile[r * 72 + cc + 8] = s[1];
    }
    __syncthreads();
    const int i = tid >> 2, jc = (tid & 3) * 16;
    alignas(16) u16 o[16];
#pragma unroll
    for (int j = 0; j < 16; ++j) o[j] = tile[(jc + j) * 72 + i];
    uint4* dq = (uint4*)&out[(size_t)(c0 + i) * R + r0 + jc];
    dq[0] = ((const uint4*)o)[0];
    dq[1] = ((const uint4*)o)[1];
  }
}

// ---------------- merged GEMM1 (+ embedded ystats blocks) -------------------
// h_{mu,lv} = relu(x @ [W1m|W1l] + b1). Round-6 proven GEMM structure:
// 128x128 tile, BK=64, XOR-swizzled LDS, XCD-aware decode on (id-64).
// Blocks [0,64): y column stats (paired-col vector loads, 4-row unroll) —
// their load/atomic latency hides under the other 2048 blocks' MFMA work.
__global__ __launch_bounds__(256) void gemm1_kernel(
    const void* __restrict__ xraw, const u16* __restrict__ xb,
    const void* __restrict__ y,
    const u16* __restrict__ W1t,    // [4096, 512]
    const float* __restrict__ bias, // [4096]
    float* __restrict__ Sy, float* __restrict__ Sy2,
    u16* __restrict__ h_mu, u16* __restrict__ h_lv) {
  constexpr int K = XD;
  __shared__ alignas(16) u16 As[128 * 64];
  __shared__ alignas(16) u16 Bs[128 * 64];
  __shared__ int sflag;

  const int tid = threadIdx.x;

  if (blockIdx.x < 64) {                    // ---- ystats blocks
    const int yf = probe_f32(y, 1024, &sflag);
    const int c0 = 2 * tid;                 // cols c0, c0+1
    const int r0 = blockIdx.x * 128;
    float s0 = 0.f, s1 = 0.f, q0 = 0.f, q1 = 0.f;
    for (int r = r0; r < r0 + 128; r += 4) {
#pragma unroll
      for (int rr = 0; rr < 4; ++rr) {
        float a, c;
        if (yf) {
          const float2 v = *(const float2*)((const float*)y + (size_t)(r + rr) * YD + c0);
          a = v.x; c = v.y;
        } else {
          const uint32_t v = *(const uint32_t*)((const u16*)y + (size_t)(r + rr) * YD + c0);
          a = bf2f((u16)(v & 0xffff)); c = bf2f((u16)(v >> 16));
        }
        s0 += a; q0 += a * a;
        s1 += c; q1 += c * c;
      }
    }
    atomicAdd(&Sy[c0], s0);      atomicAdd(&Sy2[c0], q0);
    atomicAdd(&Sy[c0 + 1], s1);  atomicAdd(&Sy2[c0 + 1], q1);
    return;
  }

  const u16* A = probe_f32(xraw, 1024, &sflag) ? xb : (const u16*)xraw;

  const int wid = tid >> 6, lane = tid & 63;
  const int MT = NS / 128, NT = (2 * HD) / 128;   // 64, 32
  const int id = blockIdx.x - 64;
  const int xcd = id & 7, slot = id >> 3;
  const int bm0 = (xcd * (MT >> 3) + slot / NT) * 128;
  const int bn0 = (slot % NT) * 128;

  const int mrow = (wid >> 1) * 64, ncol = (wid & 1) * 64;
  const int quad = lane >> 4, c16 = lane & 15, cswz = c16 & 7;
  const int srow = lane >> 3, sc = lane & 7;
  const int scg  = (sc ^ srow) * 8;

  f32x4 acc[4][4] = {};

  for (int k0 = 0; k0 < K; k0 += 64) {
#pragma unroll
    for (int j = 0; j < 4; ++j) {
      const int grp = wid * 4 + j, row = grp * 8 + srow;
      GLDS(A   + (size_t)(bm0 + row) * K + (k0 + scg), As + grp * 512);
      GLDS(W1t + (size_t)(bn0 + row) * K + (k0 + scg), Bs + grp * 512);
    }
    __syncthreads();
#pragma unroll
    for (int h = 0; h < 2; ++h) {
      const int off = ((h * 4 + quad) ^ cswz) * 8;
      bf16x8 af[4], bfr[4];
#pragma unroll
      for (int mi = 0; mi < 4; ++mi)
        af[mi] = *(const bf16x8*)&As[(mrow + mi * 16 + c16) * 64 + off];
#pragma unroll
      for (int ni = 0; ni < 4; ++ni)
        bfr[ni] = *(const bf16x8*)&Bs[(ncol + ni * 16 + c16) * 64 + off];
#pragma unroll
      for (int mi = 0; mi < 4; ++mi)
#pragma unroll
        for (int ni = 0; ni < 4; ++ni)
          acc[mi][ni] = __builtin_amdgcn_mfma_f32_16x16x32_bf16(
              af[mi], bfr[ni], acc[mi][ni], 0, 0, 0);
    }
    __syncthreads();
  }

  // Epilogue (C/D layout m89: col = lane&15, row = quad*4 + reg)
  const bool is_lv = bn0 >= HD;
  u16* dst = is_lv ? h_lv : h_mu;
  const int cb = bn0 - (is_lv ? HD : 0);
#pragma unroll
  for (int ni = 0; ni < 4; ++ni) {
    const int gc = ncol + ni * 16 + c16;
    const float bv = bias[bn0 + gc];
#pragma unroll
    for (int mi = 0; mi < 4; ++mi)
#pragma unroll
      for (int r = 0; r < 4; ++r) {
        const int grow = bm0 + mrow + mi * 16 + quad * 4 + r;
        dst[(size_t)grow * HD + (cb + gc)] = f2b(fmaxf(acc[mi][ni][r] + bv, 0.f));
      }
  }
}

// ---------------- dual-head GEMM2 + fused loss + last-block finalize --------
// Round-6 proven structure: every wave computes BOTH heads on a 32x128 strip
// (dual accumulators, 32 MFMA per barrier); epilogue computes mu & lvp in
// registers -> loss directly. Last finishing block writes the output scalar.
__global__ __launch_bounds__(256) void gemm2_dual(
    const u16* __restrict__ hm, const u16* __restrict__ hl,
    const u16* __restrict__ W2m, const u16* __restrict__ W2l,  // [YD, HD]
    const float* __restrict__ b2m, const float* __restrict__ b2l,
    const void* __restrict__ y,
    const float* __restrict__ Sy, const float* __restrict__ Sy2,
    double* __restrict__ gacc, unsigned* __restrict__ counter,
    float* __restrict__ out) {
  constexpr int K = HD;
  __shared__ alignas(16) u16 Am[64 * 64];    // 8 KB
  __shared__ alignas(16) u16 Al[64 * 64];    // 8 KB
  __shared__ alignas(16) u16 Bm[128 * 64];   // 16 KB
  __shared__ alignas(16) u16 Bl[128 * 64];   // 16 KB
  __shared__ double bs[4];
  __shared__ int sflag;

  const int yf = probe_f32(y, 1024, &sflag);

  const int tid = threadIdx.x, wid = tid >> 6, lane = tid & 63;
  const int MT = NS / 64, NT = YD / 128;     // 128, 4
  const int id = blockIdx.x;
  const int xcd = id & 7, slot = id >> 3;
  const int bm0 = (xcd * (MT >> 3) + slot / NT) * 64;
  const int bn0 = (slot % NT) * 128;

  const int mrow = (wid >> 1) * 32, ncol = (wid & 1) * 64;
  const int quad = lane >> 4, c16 = lane & 15, cswz = c16 & 7;
  const int srow = lane >> 3, sc = lane & 7;
  const int scg  = (sc ^ srow) * 8;

  f32x4 am[2][4] = {}, al[2][4] = {};

  for (int k0 = 0; k0 < K; k0 += 64) {
#pragma unroll
    for (int j = 0; j < 2; ++j) {            // h tiles: 64 rows
      const int grp = wid * 2 + j, row = grp * 8 + srow;
      const size_t go = (size_t)(bm0 + row) * K + (k0 + scg);
      GLDS(hm + go, Am + grp * 512);
      GLDS(hl + go, Al + grp * 512);
    }
#pragma unroll
    for (int j = 0; j < 4; ++j) {            // W2 tiles: 128 rows
      const int grp = wid * 4 + j, row = grp * 8 + srow;
      const size_t go = (size_t)(bn0 + row) * K + (k0 + scg);
      GLDS(W2m + go, Bm + grp * 512);
      GLDS(W2l + go, Bl + grp * 512);
    }
    __syncthreads();
#pragma unroll
    for (int h = 0; h < 2; ++h) {
      const int off = ((h * 4 + quad) ^ cswz) * 8;
      bf16x8 afm[2], afl[2], bfm[4], bfl[4];
#pragma unroll
      for (int mi = 0; mi < 2; ++mi) {
        const int rl = (mrow + mi * 16 + c16) * 64 + off;
        afm[mi] = *(const bf16x8*)&Am[rl];
        afl[mi] = *(const bf16x8*)&Al[rl];
      }
#pragma unroll
      for (int ni = 0; ni < 4; ++ni) {
        const int rl = (ncol + ni * 16 + c16) * 64 + off;
        bfm[ni] = *(const bf16x8*)&Bm[rl];
        bfl[ni] = *(const bf16x8*)&Bl[rl];
      }
#pragma unroll
      for (int mi = 0; mi < 2; ++mi)
#pragma unroll
        for (int ni = 0; ni < 4; ++ni) {
          am[mi][ni] = __builtin_amdgcn_mfma_f32_16x16x32_bf16(
              afm[mi], bfm[ni], am[mi][ni], 0, 0, 0);
          al[mi][ni] = __builtin_amdgcn_mfma_f32_16x16x32_bf16(
              afl[mi], bfl[ni], al[mi][ni], 0, 0, 0);
        }
    }
    __syncthreads();
  }

  // Fused loss epilogue: mu & lvp in registers.
  // term: w * [ y^2 - 2*mu*y + (2*mu*Sy_d - Sy2_d)/N ], w = 0.5*e^{-tanh(lvp)}
  const float invN = 1.0f / (float)NS;
  float s = 0.f;
#pragma unroll
  for (int ni = 0; ni < 4; ++ni) {
    const int gcol = bn0 + ncol + ni * 16 + c16;
    const float bmv = b2m[gcol], blv = b2l[gcol];
    const float syv = Sy[gcol], sy2v = Sy2[gcol];
#pragma unroll
    for (int mi = 0; mi < 2; ++mi)
#pragma unroll
      for (int r = 0; r < 4; ++r) {
        const int grow = bm0 + mrow + mi * 16 + quad * 4 + r;
        const float m   = am[mi][ni][r] + bmv;
        const float lvp = al[mi][ni][r] + blv;
        const float w   = 0.5f * expf(-tanhf(lvp));
        const float yv  = ld_in(y, yf, (size_t)grow * YD + gcol);
        s += w * (yv * yv - 2.f * m * yv + (2.f * m * syv - sy2v) * invN);
      }
  }
  for (int off = 32; off > 0; off >>= 1) s += __shfl_down(s, off);
  if (lane == 0) bs[wid] = (double)s;
  __syncthreads();
  if (tid == 0) {
    atomicAdd(gacc, bs[0] + bs[1] + bs[2] + bs[3]);
    __threadfence();
    const unsigned old = atomicAdd(counter, 1u);
    if (old == gridDim.x - 1) {              // last block -> finalize
      const double g = atomicAdd(gacc, 0.0); // coherent read of final sum
      out[0] = (float)(-g / (double)NS);     // fp32 output (round-2 evidence)
    }
  }
}

// ---------------- launch ----------------
extern "C" void kernel_launch(void* const* d_in, const int* in_sizes, int n_in,
                              void* d_out, int out_size, void* d_ws, size_t ws_size,
                              hipStream_t stream) {
  char* ws = (char*)d_ws;
  double*   gacc    = (double*)ws;               // [0,8)
  unsigned* counter = (unsigned*)(ws + 8);       // [8,12)
  float*    Sy      = (float*)(ws + 128);        // 512 f32
  float*    Sy2     = (float*)(ws + 2176);       // 512 f32
  float*    biasv   = (float*)(ws + 4224);       // 5120 f32 -> ends 24704
  u16* xb   = (u16*)(ws + 24704);                // [NS,XD] bf16, 8 MB
  u16* W1t  = xb + (size_t)NS * XD;              // [4096,512] 4 MB (both heads)
  u16* W2tm = W1t + (size_t)2 * HD * XD;         // [YD,HD] 2 MB
  u16* W2tl = W2tm + (size_t)YD * HD;            // 2 MB
  u16* h_mu = W2tl + (size_t)YD * HD;            // [NS,HD] bf16, 32 MB
  u16* h_lv = h_mu + (size_t)NS * HD;            // 32 MB  (~80 MB total)

  hipMemsetAsync(d_ws, 0, 4224, stream);         // gacc + counter + Sy + Sy2

  prep_all<<<2049 + 1024, 256, 0, stream>>>(
      d_in[0], d_in[2], d_in[3], d_in[4], d_in[5],
      d_in[6], d_in[7], d_in[8], d_in[9],
      xb, biasv, W1t, W2tm, W2tl);

  const float* b1  = biasv;               // [4096] = b1m|b1l
  const float* b2m = biasv + 4096, *b2l = biasv + 4608;

  gemm1_kernel<<<64 + (NS / 128) * ((2 * HD) / 128), 256, 0, stream>>>(
      d_in[0], xb, d_in[1], W1t, b1, Sy, Sy2, h_mu, h_lv);

  gemm2_dual<<<(NS / 64) * (YD / 128), 256, 0, stream>>>(
      h_mu, h_lv, W2tm, W2tl, b2m, b2l, d_in[1], Sy, Sy2,
      gacc, counter, (float*)d_out);
}

// Round 10
// 228.919 us; speedup vs baseline: 1.3442x; 1.0053x over previous
//
#include <hip/hip_runtime.h>
#include <hip/hip_bf16.h>
#include <stdint.h>

// Problem constants (fixed by the reference)
#define NS   8192
#define XD   512
#define HD   2048
#define YD   512

typedef unsigned short u16;
using bf16x8 = __attribute__((ext_vector_type(8))) short;
using f32x4  = __attribute__((ext_vector_type(4))) float;

__device__ __forceinline__ float bf2f(u16 u) {
  union { uint32_t i; float f; } v; v.i = ((uint32_t)u) << 16; return v.f;
}
__device__ __forceinline__ u16 f2b(float f) {
  __hip_bfloat16 hb = __float2bfloat16(f);
  return *(const u16*)&hb;
}
// dtype-adaptive element load: f32 flag ? read float : read bf16
__device__ __forceinline__ float ld_in(const void* p, int f32, size_t i) {
  return f32 ? ((const float*)p)[i] : bf2f(((const u16*)p)[i]);
}
#define GLDS(gp, lp) __builtin_amdgcn_global_load_lds( \
    (__attribute__((address_space(1))) void*)(gp),     \
    (__attribute__((address_space(3))) void*)(lp), 16, 0, 0)

// ---------------- per-block dtype self-detection ----------------------------
// (round-2/3 lesson: inputs are MIXED dtype; cross-round accounting says
// x,y = fp32, weights = bf16 — but stay adaptive). fp32 bits read as bf16 are
// wild/NaN with p~0.46 per low-u16 -> 256+ sample probe is conclusive.
__device__ __forceinline__ int probe_f32(const void* p, int n_u16, int* sflag) {
  if (threadIdx.x == 0) *sflag = 0;
  __syncthreads();
  const u16* q = (const u16*)p;
  int wild = 0;
  for (int i = threadIdx.x; i < n_u16; i += blockDim.x) {
    float v = bf2f(q[i]);
    if (!(fabsf(v) <= 1000.0f)) wild = 1;   // catches huge AND NaN
  }
  if (wild) *sflag = 1;
  __syncthreads();
  int r = *sflag;
  __syncthreads();                          // safe for back-to-back reuse
  return r;
}

// ---------------- fused prep: x->bf16, biases, 4 transposes -----------------
// grid: [0,2048) x-convert | 2048 biases | [2049, 2049+1024) transposes
// biasv layout: [b1m(2048) | b1l(2048) | b2m(512) | b2l(512)]
// W1t combined: [4096, 512] = W1m^T rows 0..2047, W1l^T rows 2048..4095.
__global__ __launch_bounds__(256) void prep_all(
    const void* __restrict__ x,
    const void* w1m, const void* b1m, const void* w2m, const void* b2m,
    const void* w1l, const void* b1l, const void* w2l, const void* b2l,
    u16* __restrict__ xb, float* __restrict__ biasv,
    u16* __restrict__ W1t, u16* __restrict__ W2tm, u16* __restrict__ W2tl) {
  __shared__ u16 tile[64 * 72];              // transpose staging (9216 B)
  __shared__ int sflag;
  const int b = blockIdx.x;
  const int tid = threadIdx.x;

  if (b < 2048) {                            // ---- x conversion (f32 only)
    if (!probe_f32(x, 1024, &sflag)) return; // bf16 -> gemm1 reads x directly
    const size_t base = (size_t)b * 2048 + (size_t)tid * 8;
    alignas(16) u16 o[8];
    const float4* s = (const float4*)((const float*)x + base);
    float4 v0 = s[0], v1 = s[1];
    o[0]=f2b(v0.x); o[1]=f2b(v0.y); o[2]=f2b(v0.z); o[3]=f2b(v0.w);
    o[4]=f2b(v1.x); o[5]=f2b(v1.y); o[6]=f2b(v1.z); o[7]=f2b(v1.w);
    *(uint4*)(xb + base) = *(const uint4*)o;
  } else if (b == 2048) {                    // ---- biases -> f32
    const int f3 = probe_f32(b1m, 1024, &sflag);
    const int f5 = probe_f32(b2m, 512, &sflag);
    const int f7 = probe_f32(b1l, 1024, &sflag);
    const int f9 = probe_f32(b2l, 512, &sflag);
    for (int i = tid; i < 5120; i += 256) {
      float v;
      if (i < 2048)      v = ld_in(b1m, f3, i);
      else if (i < 4096) v = ld_in(b1l, f7, i - 2048);
      else if (i < 4608) v = ld_in(b2m, f5, i - 4096);
      else               v = ld_in(b2l, f9, i - 4608);
      biasv[i] = v;
    }
  } else {                                   // ---- 64x64-tile transposes
    const int id = b - 2049, which = id >> 8, t = id & 255;
    const void* in; u16* out; int R, C;
    if (which == 0)      { in = w1m; out = W1t;                   R = XD; C = HD; }
    else if (which == 1) { in = w2m; out = W2tm;                  R = HD; C = YD; }
    else if (which == 2) { in = w1l; out = W1t + (size_t)HD * XD; R = XD; C = HD; }
    else                 { in = w2l; out = W2tl;                  R = HD; C = YD; }
    const int f = probe_f32(in, 1024, &sflag);
    const int nbx = C >> 6;
    const int c0 = (t % nbx) * 64, r0 = (t / nbx) * 64;
    const int r = tid >> 2, cc = (tid & 3) * 16;
    if (f) {
      const float4* s = (const float4*)((const float*)in + (size_t)(r0 + r) * C + c0 + cc);
#pragma unroll
      for (int k = 0; k < 4; ++k) {
        float4 v = s[k];
        tile[r * 72 + cc + k * 4 + 0] = f2b(v.x);
        tile[r * 72 + cc + k * 4 + 1] = f2b(v.y);
        tile[r * 72 + cc + k * 4 + 2] = f2b(v.z);
        tile[r * 72 + cc + k * 4 + 3] = f2b(v.w);
      }
    } else {
      const uint4* s = (const uint4*)((const u16*)in + (size_t)(r0 + r) * C + c0 + cc);
      *(uint4*)&tile[r * 72 + cc]     = s[0];
      *(uint4*)&tile[r * 72 + cc + 8] = s[1];
    }
    __syncthreads();
    const int i = tid >> 2, jc = (tid & 3) * 16;
    alignas(16) u16 o[16];
#pragma unroll
    for (int j = 0; j < 16; ++j) o[j] = tile[(jc + j) * 72 + i];
    uint4* dq = (uint4*)&out[(size_t)(c0 + i) * R + r0 + jc];
    dq[0] = ((const uint4*)o)[0];
    dq[1] = ((const uint4*)o)[1];
  }
}

// ---------------- merged GEMM1 (+ embedded ystats blocks) -------------------
// h_{mu,lv} = relu(x @ [W1m|W1l] + b1). 128x128 tile, BK=64, XOR-swizzled
// LDS. Round-10: M-FASTEST decode within each XCD — x-slab (1 MB) stays
// L2-resident across all n-tiles while each W1t n-tile (128 KB) streams once
// (N-fastest swept all 4 MB of W1t per m-group -> L2 thrash, FETCH 82.5 MB).
// Blocks [0,64): y column stats, 4 cols x float4 x 4-row unroll (16
// outstanding 16-B loads; round-9's 2-col version was a ~20 us latency chain).
__global__ __launch_bounds__(256) void gemm1_kernel(
    const void* __restrict__ xraw, const u16* __restrict__ xb,
    const void* __restrict__ y,
    const u16* __restrict__ W1t,    // [4096, 512]
    const float* __restrict__ bias, // [4096]
    float* __restrict__ Sy, float* __restrict__ Sy2,
    u16* __restrict__ h_mu, u16* __restrict__ h_lv) {
  constexpr int K = XD;
  __shared__ alignas(16) u16 As[128 * 64];
  __shared__ alignas(16) u16 Bs[128 * 64];
  __shared__ int sflag;

  const int tid = threadIdx.x;

  if (blockIdx.x < 64) {                    // ---- ystats blocks
    const int yf = probe_f32(y, 1024, &sflag);
    const int half = tid >> 7;              // 0/1: rows r0..+63 / r0+64..+127
    const int c0 = (tid & 127) * 4;         // cols c0..c0+3
    const int r0 = blockIdx.x * 128 + half * 64;
    float s0 = 0.f, s1 = 0.f, s2 = 0.f, s3 = 0.f;
    float q0 = 0.f, q1 = 0.f, q2 = 0.f, q3 = 0.f;
    for (int r = r0; r < r0 + 64; r += 4) {
#pragma unroll
      for (int rr = 0; rr < 4; ++rr) {
        float v0, v1, v2, v3;
        if (yf) {
          const float4 t4 = *(const float4*)((const float*)y + (size_t)(r + rr) * YD + c0);
          v0 = t4.x; v1 = t4.y; v2 = t4.z; v3 = t4.w;
        } else {
          const uint2 t2 = *(const uint2*)((const u16*)y + (size_t)(r + rr) * YD + c0);
          v0 = bf2f((u16)(t2.x & 0xffff)); v1 = bf2f((u16)(t2.x >> 16));
          v2 = bf2f((u16)(t2.y & 0xffff)); v3 = bf2f((u16)(t2.y >> 16));
        }
        s0 += v0; q0 += v0 * v0;  s1 += v1; q1 += v1 * v1;
        s2 += v2; q2 += v2 * v2;  s3 += v3; q3 += v3 * v3;
      }
    }
    atomicAdd(&Sy[c0],     s0);  atomicAdd(&Sy2[c0],     q0);
    atomicAdd(&Sy[c0 + 1], s1);  atomicAdd(&Sy2[c0 + 1], q1);
    atomicAdd(&Sy[c0 + 2], s2);  atomicAdd(&Sy2[c0 + 2], q2);
    atomicAdd(&Sy[c0 + 3], s3);  atomicAdd(&Sy2[c0 + 3], q3);
    return;
  }

  const u16* A = probe_f32(xraw, 1024, &sflag) ? xb : (const u16*)xraw;

  const int wid = tid >> 6, lane = tid & 63;
  const int id = blockIdx.x - 64;
  const int xcd = id & 7, slot = id >> 3;
  const int m_idx = slot & 7;               // M fastest (8 m-tiles per XCD)
  const int n_idx = slot >> 3;              // 0..31, advances slowly
  const int bm0 = (xcd * 8 + m_idx) * 128;
  const int bn0 = n_idx * 128;

  const int mrow = (wid >> 1) * 64, ncol = (wid & 1) * 64;
  const int quad = lane >> 4, c16 = lane & 15, cswz = c16 & 7;
  const int srow = lane >> 3, sc = lane & 7;
  const int scg  = (sc ^ srow) * 8;

  f32x4 acc[4][4] = {};

  for (int k0 = 0; k0 < K; k0 += 64) {
#pragma unroll
    for (int j = 0; j < 4; ++j) {
      const int grp = wid * 4 + j, row = grp * 8 + srow;
      GLDS(A   + (size_t)(bm0 + row) * K + (k0 + scg), As + grp * 512);
      GLDS(W1t + (size_t)(bn0 + row) * K + (k0 + scg), Bs + grp * 512);
    }
    __syncthreads();
#pragma unroll
    for (int h = 0; h < 2; ++h) {
      const int off = ((h * 4 + quad) ^ cswz) * 8;
      bf16x8 af[4], bfr[4];
#pragma unroll
      for (int mi = 0; mi < 4; ++mi)
        af[mi] = *(const bf16x8*)&As[(mrow + mi * 16 + c16) * 64 + off];
#pragma unroll
      for (int ni = 0; ni < 4; ++ni)
        bfr[ni] = *(const bf16x8*)&Bs[(ncol + ni * 16 + c16) * 64 + off];
#pragma unroll
      for (int mi = 0; mi < 4; ++mi)
#pragma unroll
        for (int ni = 0; ni < 4; ++ni)
          acc[mi][ni] = __builtin_amdgcn_mfma_f32_16x16x32_bf16(
              af[mi], bfr[ni], acc[mi][ni], 0, 0, 0);
    }
    __syncthreads();
  }

  // Epilogue (C/D layout m89: col = lane&15, row = quad*4 + reg)
  const bool is_lv = bn0 >= HD;
  u16* dst = is_lv ? h_lv : h_mu;
  const int cb = bn0 - (is_lv ? HD : 0);
#pragma unroll
  for (int ni = 0; ni < 4; ++ni) {
    const int gc = ncol + ni * 16 + c16;
    const float bv = bias[bn0 + gc];
#pragma unroll
    for (int mi = 0; mi < 4; ++mi)
#pragma unroll
      for (int r = 0; r < 4; ++r) {
        const int grow = bm0 + mrow + mi * 16 + quad * 4 + r;
        dst[(size_t)grow * HD + (cb + gc)] = f2b(fmaxf(acc[mi][ni][r] + bv, 0.f));
      }
  }
}

// ---------------- dual-head GEMM2 + fused loss + last-block finalize --------
// Round-6 proven structure: every wave computes BOTH heads on a 32x128 strip
// (dual accumulators, 32 MFMA per barrier); epilogue computes mu & lvp in
// registers -> loss directly. N-fastest kept here: the 4 n-tiles of one
// m-group share the 512 KB h-slab in L2. Last finishing block writes out.
__global__ __launch_bounds__(256) void gemm2_dual(
    const u16* __restrict__ hm, const u16* __restrict__ hl,
    const u16* __restrict__ W2m, const u16* __restrict__ W2l,  // [YD, HD]
    const float* __restrict__ b2m, const float* __restrict__ b2l,
    const void* __restrict__ y,
    const float* __restrict__ Sy, const float* __restrict__ Sy2,
    double* __restrict__ gacc, unsigned* __restrict__ counter,
    float* __restrict__ out) {
  constexpr int K = HD;
  __shared__ alignas(16) u16 Am[64 * 64];    // 8 KB
  __shared__ alignas(16) u16 Al[64 * 64];    // 8 KB
  __shared__ alignas(16) u16 Bm[128 * 64];   // 16 KB
  __shared__ alignas(16) u16 Bl[128 * 64];   // 16 KB
  __shared__ double bs[4];
  __shared__ int sflag;

  const int yf = probe_f32(y, 1024, &sflag);

  const int tid = threadIdx.x, wid = tid >> 6, lane = tid & 63;
  const int MT = NS / 64, NT = YD / 128;     // 128, 4
  const int id = blockIdx.x;
  const int xcd = id & 7, slot = id >> 3;
  const int bm0 = (xcd * (MT >> 3) + slot / NT) * 64;
  const int bn0 = (slot % NT) * 128;

  const int mrow = (wid >> 1) * 32, ncol = (wid & 1) * 64;
  const int quad = lane >> 4, c16 = lane & 15, cswz = c16 & 7;
  const int srow = lane >> 3, sc = lane & 7;
  const int scg  = (sc ^ srow) * 8;

  f32x4 am[2][4] = {}, al[2][4] = {};

  for (int k0 = 0; k0 < K; k0 += 64) {
#pragma unroll
    for (int j = 0; j < 2; ++j) {            // h tiles: 64 rows
      const int grp = wid * 2 + j, row = grp * 8 + srow;
      const size_t go = (size_t)(bm0 + row) * K + (k0 + scg);
      GLDS(hm + go, Am + grp * 512);
      GLDS(hl + go, Al + grp * 512);
    }
#pragma unroll
    for (int j = 0; j < 4; ++j) {            // W2 tiles: 128 rows
      const int grp = wid * 4 + j, row = grp * 8 + srow;
      const size_t go = (size_t)(bn0 + row) * K + (k0 + scg);
      GLDS(W2m + go, Bm + grp * 512);
      GLDS(W2l + go, Bl + grp * 512);
    }
    __syncthreads();
#pragma unroll
    for (int h = 0; h < 2; ++h) {
      const int off = ((h * 4 + quad) ^ cswz) * 8;
      bf16x8 afm[2], afl[2], bfm[4], bfl[4];
#pragma unroll
      for (int mi = 0; mi < 2; ++mi) {
        const int rl = (mrow + mi * 16 + c16) * 64 + off;
        afm[mi] = *(const bf16x8*)&Am[rl];
        afl[mi] = *(const bf16x8*)&Al[rl];
      }
#pragma unroll
      for (int ni = 0; ni < 4; ++ni) {
        const int rl = (ncol + ni * 16 + c16) * 64 + off;
        bfm[ni] = *(const bf16x8*)&Bm[rl];
        bfl[ni] = *(const bf16x8*)&Bl[rl];
      }
#pragma unroll
      for (int mi = 0; mi < 2; ++mi)
#pragma unroll
        for (int ni = 0; ni < 4; ++ni) {
          am[mi][ni] = __builtin_amdgcn_mfma_f32_16x16x32_bf16(
              afm[mi], bfm[ni], am[mi][ni], 0, 0, 0);
          al[mi][ni] = __builtin_amdgcn_mfma_f32_16x16x32_bf16(
              afl[mi], bfl[ni], al[mi][ni], 0, 0, 0);
        }
    }
    __syncthreads();
  }

  // Fused loss epilogue: mu & lvp in registers.
  // term: w * [ y^2 - 2*mu*y + (2*mu*Sy_d - Sy2_d)/N ], w = 0.5*e^{-tanh(lvp)}
  const float invN = 1.0f / (float)NS;
  float s = 0.f;
#pragma unroll
  for (int ni = 0; ni < 4; ++ni) {
    const int gcol = bn0 + ncol + ni * 16 + c16;
    const float bmv = b2m[gcol], blv = b2l[gcol];
    const float syv = Sy[gcol], sy2v = Sy2[gcol];
#pragma unroll
    for (int mi = 0; mi < 2; ++mi)
#pragma unroll
      for (int r = 0; r < 4; ++r) {
        const int grow = bm0 + mrow + mi * 16 + quad * 4 + r;
        const float m   = am[mi][ni][r] + bmv;
        const float lvp = al[mi][ni][r] + blv;
        const float w   = 0.5f * expf(-tanhf(lvp));
        const float yv  = ld_in(y, yf, (size_t)grow * YD + gcol);
        s += w * (yv * yv - 2.f * m * yv + (2.f * m * syv - sy2v) * invN);
      }
  }
  for (int off = 32; off > 0; off >>= 1) s += __shfl_down(s, off);
  if (lane == 0) bs[wid] = (double)s;
  __syncthreads();
  if (tid == 0) {
    atomicAdd(gacc, bs[0] + bs[1] + bs[2] + bs[3]);
    __threadfence();
    const unsigned old = atomicAdd(counter, 1u);
    if (old == gridDim.x - 1) {              // last block -> finalize
      const double g = atomicAdd(gacc, 0.0); // coherent read of final sum
      out[0] = (float)(-g / (double)NS);     // fp32 output (round-2 evidence)
    }
  }
}

// ---------------- launch ----------------
extern "C" void kernel_launch(void* const* d_in, const int* in_sizes, int n_in,
                              void* d_out, int out_size, void* d_ws, size_t ws_size,
                              hipStream_t stream) {
  char* ws = (char*)d_ws;
  double*   gacc    = (double*)ws;               // [0,8)
  unsigned* counter = (unsigned*)(ws + 8);       // [8,12)
  float*    Sy      = (float*)(ws + 128);        // 512 f32
  float*    Sy2     = (float*)(ws + 2176);       // 512 f32
  float*    biasv   = (float*)(ws + 4224);       // 5120 f32 -> ends 24704
  u16* xb   = (u16*)(ws + 24704);                // [NS,XD] bf16, 8 MB
  u16* W1t  = xb + (size_t)NS * XD;              // [4096,512] 4 MB (both heads)
  u16* W2tm = W1t + (size_t)2 * HD * XD;         // [YD,HD] 2 MB
  u16* W2tl = W2tm + (size_t)YD * HD;            // 2 MB
  u16* h_mu = W2tl + (size_t)YD * HD;            // [NS,HD] bf16, 32 MB
  u16* h_lv = h_mu + (size_t)NS * HD;            // 32 MB  (~80 MB total)

  hipMemsetAsync(d_ws, 0, 4224, stream);         // gacc + counter + Sy + Sy2

  prep_all<<<2049 + 1024, 256, 0, stream>>>(
      d_in[0], d_in[2], d_in[3], d_in[4], d_in[5],
      d_in[6], d_in[7], d_in[8], d_in[9],
      xb, biasv, W1t, W2tm, W2tl);

  const float* b1  = biasv;               // [4096] = b1m|b1l
  const float* b2m = biasv + 4096, *b2l = biasv + 4608;

  gemm1_kernel<<<64 + (NS / 128) * ((2 * HD) / 128), 256, 0, stream>>>(
      d_in[0], xb, d_in[1], W1t, b1, Sy, Sy2, h_mu, h_lv);

  gemm2_dual<<<(NS / 64) * (YD / 128), 256, 0, stream>>>(
      h_mu, h_lv, W2tm, W2tl, b2m, b2l, d_in[1], Sy, Sy2,
      gacc, counter, (float*)d_out);
}